// Round 3
// baseline (141.361 us; speedup 1.0000x reference)
//
#include <hip/hip_runtime.h>
#include <math.h>

#define NB 2048
#define LL 200
#define DD 64
#define CC 9
#define HH 16
#define NW 4   // waves per block

__global__ __launch_bounds__(256) void din_fwd(
    const int* __restrict__ user_inputs,     // [B]
    const int* __restrict__ record_inputs,   // [B,L]
    const int* __restrict__ item_inputs,     // [B]
    const int* __restrict__ item_cat,        // [NUM_ITEMS]
    const float* __restrict__ user_emb,      // [NU,D]
    const float* __restrict__ item_emb,      // [NI,D]
    const float* __restrict__ W1,            // [C,H,2D]
    const float* __restrict__ b1,            // [C,H]
    const float* __restrict__ W2,            // [C,1,H]
    const float* __restrict__ b2,            // [C,1]
    const float* __restrict__ Wt1,           // [H,2D]
    const float* __restrict__ bt1,           // [H]
    const float* __restrict__ Wt2,           // [1,H]
    const float* __restrict__ bt2,           // [1]
    float* __restrict__ out)                 // [B]
{
  const int b = blockIdx.x;
  const int t = threadIdx.x;
  const int wave = t >> 6, lane = t & 63;

  __shared__ float u_s[DD];
  __shared__ float pre_s[CC][HH];
  __shared__ int   scat[LL];
  __shared__ int   srow[LL];
  __shared__ float s_s[LL];
  __shared__ float w_s[LL];
  __shared__ int   cstart[CC + 1];
  __shared__ float cinv[CC];
  __shared__ int   cnt_s[CC];
  __shared__ int   wcnt[NW][CC];
  __shared__ float gvec_s[CC][DD];
  __shared__ float h2_s[CC][HH];
  __shared__ float w2_s[CC];

  // ---- Phase 0: global loads + ballot-based stable counting sort ----
  int r = -1, c0 = -1;
  if (t < LL) {
    r = record_inputs[b * LL + t];
    if (r >= 0) c0 = item_cat[r];
  }
  if (t < DD) u_s[t] = user_emb[(size_t)user_inputs[b] * DD + t];

  int myrank = 0;
  #pragma unroll
  for (int c = 0; c < CC; ++c) {
    unsigned long long m = __ballot(c0 == c);
    if (lane == 0) wcnt[wave][c] = __popcll(m);
    if (c0 == c) myrank = __popcll(m & ((1ULL << lane) - 1ULL));
  }
  __syncthreads();   // u_s, wcnt visible

  // 9-way prefix (thread 0) + user-half of MLP (pre = W1u*u + b1)
  if (t == 0) {
    int acc = 0;
    #pragma unroll
    for (int c = 0; c < CC; ++c) {
      cstart[c] = acc;
      int tot = wcnt[0][c] + wcnt[1][c] + wcnt[2][c] + wcnt[3][c];
      cnt_s[c] = tot;
      acc += tot;
    }
    cstart[CC] = acc;
  }
  if (t < CC * HH) {
    int c = t / HH, j = t % HH;
    const float* wp = &W1[(size_t)(c * HH + j) * (2 * DD)];
    float acc = b1[c * HH + j];
    #pragma unroll 8
    for (int d = 0; d < DD; ++d) acc += wp[d] * u_s[d];
    pre_s[c][j] = acc;
  }
  __syncthreads();   // cstart visible

  // stable scatter: pos = cstart[c] + (ranks of earlier waves) + in-wave rank
  if (c0 >= 0) {
    int off = cstart[c0];
    for (int w = 0; w < wave; ++w) off += wcnt[w][c0];
    int pos = off + myrank;
    scat[pos] = c0;
    srow[pos] = r;
  }
  __syncthreads();   // scat/srow/pre_s visible

  const int nvalid = cstart[CC];

  // ---- Phase 1: per-item MLP score, i-outer / j-inner, e loaded ONCE ----
  if (t < nvalid) {
    int c = scat[t];
    int row = srow[t];
    const float4* ep = (const float4*)&item_emb[(size_t)row * DD];
    // W1 e-half for category c: row j at wbase[j*32 + i] (float4 units)
    const float4* wbase = (const float4*)&W1[(size_t)c * HH * (2 * DD) + DD];

    float acc[HH];
    #pragma unroll
    for (int j = 0; j < HH; ++j) acc[j] = pre_s[c][j];

    #pragma unroll
    for (int i = 0; i < 16; ++i) {
      float4 ev = ep[i];
      #pragma unroll
      for (int j = 0; j < HH; ++j) {
        float4 wv = wbase[j * 32 + i];
        acc[j] += wv.x * ev.x + wv.y * ev.y + wv.z * ev.z + wv.w * ev.w;
      }
    }
    float s = b2[c];
    #pragma unroll
    for (int j = 0; j < HH; ++j) s += W2[c * HH + j] * fmaxf(acc[j], 0.f);
    s_s[t] = s;
  }
  __syncthreads();

  // ---- Phase 2: masked softmax per category (small ranges) ----
  if (t < CC) {
    int i0 = cstart[t], i1 = cstart[t + 1];
    float m = -INFINITY;
    for (int i = i0; i < i1; ++i) m = fmaxf(m, s_s[i]);
    float sum = 0.f;
    for (int i = i0; i < i1; ++i) {
      float z = expf(s_s[i] - m);
      w_s[i] = z;
      sum += z;
    }
    cinv[t] = 1.f / fmaxf(sum, 1e-30f);
  }
  __syncthreads();

  // ---- Phase 3: gvec[c][d] = inv_c * sum_i z_i * e_i[d]  (wave per cat) ----
  for (int c = wave; c < CC; c += NW) {
    float acc = 0.f;
    int i0 = cstart[c], i1 = cstart[c + 1];
    for (int i = i0; i < i1; ++i) {
      acc += w_s[i] * item_emb[(size_t)srow[i] * DD + lane];
    }
    gvec_s[c][lane] = acc * cinv[c];   // empty cat: 0
  }
  __syncthreads();

  // ---- Phase 4: top-level attention ----
  if (t < CC * HH) {
    int c = t / HH, j = t % HH;
    const float* wp = &Wt1[(size_t)j * (2 * DD)];
    float acc = bt1[j];
    #pragma unroll 8
    for (int d = 0; d < DD; ++d) acc += wp[d] * u_s[d];
    #pragma unroll 8
    for (int d = 0; d < DD; ++d) acc += wp[DD + d] * gvec_s[c][d];
    h2_s[c][j] = fmaxf(acc, 0.f);
  }
  __syncthreads();

  if (t == 0) {
    float s2[CC];
    float m = -INFINITY;
    #pragma unroll
    for (int c = 0; c < CC; ++c) {
      float acc = bt2[0];
      #pragma unroll
      for (int j = 0; j < HH; ++j) acc += Wt2[j] * h2_s[c][j];
      s2[c] = acc;
      if (cnt_s[c] > 0) m = fmaxf(m, acc);
    }
    if (m == -INFINITY) m = 0.f;
    float sum = 0.f;
    float z2[CC];
    #pragma unroll
    for (int c = 0; c < CC; ++c) {
      z2[c] = (cnt_s[c] > 0) ? expf(s2[c] - m) : 0.f;
      sum += z2[c];
    }
    float inv = 1.f / fmaxf(sum, 1e-30f);
    #pragma unroll
    for (int c = 0; c < CC; ++c) w2_s[c] = z2[c] * inv;
  }
  __syncthreads();

  // ---- Phase 5: hybrid . target_item, wave-0 reduce ----
  if (t < DD) {
    float hy = 0.f;
    #pragma unroll
    for (int c = 0; c < CC; ++c) hy += w2_s[c] * gvec_s[c][t];
    float ti = item_emb[(size_t)item_inputs[b] * DD + t];
    float prod = hy * ti;
    #pragma unroll
    for (int off = 32; off > 0; off >>= 1)
      prod += __shfl_down(prod, off, 64);
    if (t == 0) out[b] = prod;
  }
}

extern "C" void kernel_launch(void* const* d_in, const int* in_sizes, int n_in,
                              void* d_out, int out_size, void* d_ws, size_t ws_size,
                              hipStream_t stream) {
  const int*   user_inputs   = (const int*)d_in[0];
  const int*   record_inputs = (const int*)d_in[1];
  const int*   item_inputs   = (const int*)d_in[2];
  const int*   item_cat      = (const int*)d_in[3];
  const float* user_emb      = (const float*)d_in[4];
  const float* item_emb      = (const float*)d_in[5];
  const float* W1            = (const float*)d_in[6];
  const float* b1            = (const float*)d_in[7];
  const float* W2            = (const float*)d_in[8];
  const float* b2            = (const float*)d_in[9];
  const float* Wt1           = (const float*)d_in[10];
  const float* bt1           = (const float*)d_in[11];
  const float* Wt2           = (const float*)d_in[12];
  const float* bt2           = (const float*)d_in[13];
  float* out = (float*)d_out;

  din_fwd<<<NB, 256, 0, stream>>>(user_inputs, record_inputs, item_inputs, item_cat,
                                  user_emb, item_emb, W1, b1, W2, b2,
                                  Wt1, bt1, Wt2, bt2, out);
}

// Round 4
// 136.635 us; speedup vs baseline: 1.0346x; 1.0346x over previous
//
#include <hip/hip_runtime.h>
#include <math.h>

#define NB 2048
#define LL 200
#define DD 64
#define CC 9
#define HH 16
#define NW 4

// ---- d_ws layout (bytes) ----
// srow_g : int  [B*L]      @ 0          (1,638,400)
// s_g    : float[B*L]      @ 1,638,400  (1,638,400)
// cstart : int  [B*10]     @ 3,276,800  (81,920)
// gvec   : float[B*9*64]   @ 3,358,720  (4,718,592)   total ~8.1 MB

__global__ __launch_bounds__(256) void k1_score(
    const int* __restrict__ user_inputs,
    const int* __restrict__ record_inputs,
    const int* __restrict__ item_cat,
    const float* __restrict__ user_emb,
    const float* __restrict__ item_emb,
    const float* __restrict__ W1,
    const float* __restrict__ b1,
    const float* __restrict__ W2,
    const float* __restrict__ b2,
    int* __restrict__ srow_g,
    float* __restrict__ s_g,
    int* __restrict__ cstart_g)
{
  const int b = blockIdx.x;
  const int t = threadIdx.x;
  const int wave = t >> 6, lane = t & 63;

  __shared__ float u_s[DD];
  __shared__ float pre_s[CC][HH];
  __shared__ int   wcnt[NW][CC];
  __shared__ int   cstart[CC + 1];
  __shared__ int   srow_sh[LL];

  // global loads + ballot counting
  int r = -1, c0 = -1;
  if (t < LL) {
    r = record_inputs[b * LL + t];
    if (r >= 0) c0 = item_cat[r];
  }
  if (t < DD) u_s[t] = user_emb[(size_t)user_inputs[b] * DD + t];

  int myrank = 0;
  #pragma unroll
  for (int c = 0; c < CC; ++c) {
    unsigned long long m = __ballot(c0 == c);
    if (lane == 0) wcnt[wave][c] = __popcll(m);
    if (c0 == c) myrank = __popcll(m & ((1ULL << lane) - 1ULL));
  }
  __syncthreads();

  if (t == 0) {
    int acc = 0;
    #pragma unroll
    for (int c = 0; c < CC; ++c) {
      cstart[c] = acc;
      acc += wcnt[0][c] + wcnt[1][c] + wcnt[2][c] + wcnt[3][c];
    }
    cstart[CC] = acc;
  }
  if (t < CC * HH) {   // pre = b1 + W1u . u
    int c = t / HH, j = t % HH;
    const float* wp = &W1[(size_t)(c * HH + j) * (2 * DD)];
    float acc = b1[c * HH + j];
    #pragma unroll 8
    for (int d = 0; d < DD; ++d) acc += wp[d] * u_s[d];
    pre_s[c][j] = acc;
  }
  __syncthreads();

  // stable scatter (also to global for K2)
  if (c0 >= 0) {
    int off = cstart[c0];
    for (int w = 0; w < wave; ++w) off += wcnt[w][c0];
    int pos = off + myrank;
    srow_sh[pos] = r;
    srow_g[b * LL + pos] = r;
  }
  if (t < CC + 1) cstart_g[b * 10 + t] = cstart[t];
  __syncthreads();

  const int nvalid = cstart[CC];

  // per-item MLP score: e loaded once, i-outer / j-inner
  if (t < nvalid) {
    int c = 0;
    #pragma unroll
    for (int q = 0; q < CC - 1; ++q) c += (t >= cstart[q + 1]) ? 1 : 0;
    int row = srow_sh[t];
    const float4* ep = (const float4*)&item_emb[(size_t)row * DD];
    const float4* wbase = (const float4*)&W1[(size_t)c * HH * (2 * DD) + DD];

    float acc[HH];
    #pragma unroll
    for (int j = 0; j < HH; ++j) acc[j] = pre_s[c][j];

    #pragma unroll
    for (int i = 0; i < 16; ++i) {
      float4 ev = ep[i];
      #pragma unroll
      for (int j = 0; j < HH; ++j) {
        float4 wv = wbase[j * 32 + i];
        acc[j] += wv.x * ev.x + wv.y * ev.y + wv.z * ev.z + wv.w * ev.w;
      }
    }
    float s = b2[c];
    #pragma unroll
    for (int j = 0; j < HH; ++j) s += W2[c * HH + j] * fmaxf(acc[j], 0.f);
    s_g[b * LL + t] = s;
  }
}

// one wave per (b,c): masked softmax + weighted sum of item rows
__global__ __launch_bounds__(256) void k2_gvec(
    const float* __restrict__ item_emb,
    const int* __restrict__ srow_g,
    const float* __restrict__ s_g,
    const int* __restrict__ cstart_g,
    float* __restrict__ gvec_g)
{
  const int pair = blockIdx.x * NW + (threadIdx.x >> 6);   // [0, B*C)
  const int lane = threadIdx.x & 63;
  const int b = pair / CC;
  const int c = pair - b * CC;
  const int base = b * LL;

  const int i0 = cstart_g[b * 10 + c];
  const int i1 = cstart_g[b * 10 + c + 1];
  const int n  = i1 - i0;

  float outv = 0.f;
  if (n > 0) {
    float m = -INFINITY;
    for (int i = i0 + lane; i < i1; i += 64) m = fmaxf(m, s_g[base + i]);
    #pragma unroll
    for (int off = 32; off > 0; off >>= 1) m = fmaxf(m, __shfl_xor(m, off, 64));

    float zs = 0.f;
    for (int i = i0 + lane; i < i1; i += 64) zs += expf(s_g[base + i] - m);
    #pragma unroll
    for (int off = 32; off > 0; off >>= 1) zs += __shfl_xor(zs, off, 64);
    float inv = 1.f / fmaxf(zs, 1e-30f);

    float acc = 0.f;
    for (int i = i0; i < i1; ++i) {
      float w = expf(s_g[base + i] - m);
      int row = srow_g[base + i];
      acc += w * item_emb[(size_t)row * DD + lane];
    }
    outv = acc * inv;
  }
  gvec_g[(size_t)pair * DD + lane] = outv;
}

// per-user top-level attention + output
__global__ __launch_bounds__(256) void k3_top(
    const int* __restrict__ user_inputs,
    const int* __restrict__ item_inputs,
    const float* __restrict__ user_emb,
    const float* __restrict__ item_emb,
    const float* __restrict__ Wt1,
    const float* __restrict__ bt1,
    const float* __restrict__ Wt2,
    const float* __restrict__ bt2,
    const int* __restrict__ cstart_g,
    const float* __restrict__ gvec_g,
    float* __restrict__ out)
{
  const int b = blockIdx.x;
  const int t = threadIdx.x;

  __shared__ float u_s[DD];
  __shared__ float g_s[CC * DD];
  __shared__ float h2_s[CC][HH];
  __shared__ float w2_s[CC];
  __shared__ int   cnt_s[CC];

  if (t < DD) u_s[t] = user_emb[(size_t)user_inputs[b] * DD + t];
  for (int x = t; x < CC * DD; x += 256) g_s[x] = gvec_g[(size_t)b * CC * DD + x];
  if (t < CC) cnt_s[t] = cstart_g[b * 10 + t + 1] - cstart_g[b * 10 + t];
  __syncthreads();

  if (t < CC * HH) {
    int c = t / HH, j = t % HH;
    const float* wp = &Wt1[(size_t)j * (2 * DD)];
    float acc = bt1[j];
    #pragma unroll 8
    for (int d = 0; d < DD; ++d) acc += wp[d] * u_s[d];
    #pragma unroll 8
    for (int d = 0; d < DD; ++d) acc += wp[DD + d] * g_s[c * DD + d];
    h2_s[c][j] = fmaxf(acc, 0.f);
  }
  __syncthreads();

  if (t == 0) {
    float s2[CC];
    float m = -INFINITY;
    #pragma unroll
    for (int c = 0; c < CC; ++c) {
      float acc = bt2[0];
      #pragma unroll
      for (int j = 0; j < HH; ++j) acc += Wt2[j] * h2_s[c][j];
      s2[c] = acc;
      if (cnt_s[c] > 0) m = fmaxf(m, acc);
    }
    if (m == -INFINITY) m = 0.f;
    float sum = 0.f;
    float z2[CC];
    #pragma unroll
    for (int c = 0; c < CC; ++c) {
      z2[c] = (cnt_s[c] > 0) ? expf(s2[c] - m) : 0.f;
      sum += z2[c];
    }
    float inv = 1.f / fmaxf(sum, 1e-30f);
    #pragma unroll
    for (int c = 0; c < CC; ++c) w2_s[c] = z2[c] * inv;
  }
  __syncthreads();

  if (t < DD) {
    float hy = 0.f;
    #pragma unroll
    for (int c = 0; c < CC; ++c) hy += w2_s[c] * g_s[c * DD + t];
    float ti = item_emb[(size_t)item_inputs[b] * DD + t];
    float prod = hy * ti;
    #pragma unroll
    for (int off = 32; off > 0; off >>= 1)
      prod += __shfl_down(prod, off, 64);
    if (t == 0) out[b] = prod;
  }
}

extern "C" void kernel_launch(void* const* d_in, const int* in_sizes, int n_in,
                              void* d_out, int out_size, void* d_ws, size_t ws_size,
                              hipStream_t stream) {
  const int*   user_inputs   = (const int*)d_in[0];
  const int*   record_inputs = (const int*)d_in[1];
  const int*   item_inputs   = (const int*)d_in[2];
  const int*   item_cat      = (const int*)d_in[3];
  const float* user_emb      = (const float*)d_in[4];
  const float* item_emb      = (const float*)d_in[5];
  const float* W1            = (const float*)d_in[6];
  const float* b1            = (const float*)d_in[7];
  const float* W2            = (const float*)d_in[8];
  const float* b2            = (const float*)d_in[9];
  const float* Wt1           = (const float*)d_in[10];
  const float* bt1           = (const float*)d_in[11];
  const float* Wt2           = (const float*)d_in[12];
  const float* bt2           = (const float*)d_in[13];
  float* out = (float*)d_out;

  char* ws = (char*)d_ws;
  int*   srow_g   = (int*)(ws);                          // B*L ints
  float* s_g      = (float*)(ws + 1638400);              // B*L floats
  int*   cstart_g = (int*)(ws + 3276800);                // B*10 ints
  float* gvec_g   = (float*)(ws + 3358720);              // B*C*D floats

  k1_score<<<NB, 256, 0, stream>>>(user_inputs, record_inputs, item_cat,
                                   user_emb, item_emb, W1, b1, W2, b2,
                                   srow_g, s_g, cstart_g);
  k2_gvec<<<(NB * CC) / NW, 256, 0, stream>>>(item_emb, srow_g, s_g, cstart_g, gvec_g);
  k3_top<<<NB, 256, 0, stream>>>(user_inputs, item_inputs, user_emb, item_emb,
                                 Wt1, bt1, Wt2, bt2, cstart_g, gvec_g, out);
}